// Round 9
// baseline (319.848 us; speedup 1.0000x reference)
//
#include <hip/hip_runtime.h>
#include <cstdint>

typedef __attribute__((ext_vector_type(8)))  short bf16x8;   // 8 x bf16 (4 VGPR)
typedef __attribute__((ext_vector_type(16))) float f32x16;   // MFMA 32x32 acc
typedef __attribute__((ext_vector_type(4)))  int   i32x4;

__device__ __forceinline__ unsigned short f2bf(float x) {    // RNE fp32->bf16
  unsigned u = __float_as_uint(x);
  u += 0x7fffu + ((u >> 16) & 1u);
  return (unsigned short)(u >> 16);
}
__device__ __forceinline__ float bf2f(unsigned short h) {
  return __uint_as_float(((unsigned)h) << 16);
}
__device__ __forceinline__ unsigned pk2bf(float lo, float hi) {
#if defined(__has_builtin)
#if __has_builtin(__builtin_amdgcn_cvt_pk_bf16_f32)
  auto v = __builtin_amdgcn_cvt_pk_bf16_f32(lo, hi);
  unsigned u; __builtin_memcpy(&u, &v, 4); return u;
#else
  return ((unsigned)f2bf(hi) << 16) | (unsigned)f2bf(lo);
#endif
#else
  return ((unsigned)f2bf(hi) << 16) | (unsigned)f2bf(lo);
#endif
}
__device__ __forceinline__ float silu_f(float v) {
  return v * __builtin_amdgcn_rcpf(1.0f + __expf(-v));
}
__device__ __forceinline__ unsigned lo_pack(unsigned x, unsigned y) {
  return __builtin_amdgcn_perm(y, x, 0x05040100u);   // x.lo16 | y.lo16<<16
}
__device__ __forceinline__ unsigned hi_pack(unsigned x, unsigned y) {
  return __builtin_amdgcn_perm(y, x, 0x07060302u);
}

// ---- pack W0/W1/W2 into MFMA B-frag order via LDS transpose (coalesced R+W).
// dest layout (shorts): [layer][kt][j(8 tiles of 32 cols)][lane(64)][8]
// B-frag (32x32x16): n = lane&31, k = 16kt + 8*(lane>>5) + jj.  K0 padded 134->144.
__global__ void pack_kernel(const float* __restrict__ W0, const float* __restrict__ W1,
                            const float* __restrict__ W2,
                            unsigned short* __restrict__ packW) {
  __shared__ float ldsF[16][257];
  const int s = blockIdx.x, tid = threadIdx.x;
  const float* W; int kmax, base, kt;
  if (s < 9)       { W = W0; kmax = 134; base = 0;      kt = s; }
  else if (s < 25) { W = W1; kmax = 256; base = 36864;  kt = s - 9; }
  else             { W = W2; kmax = 256; base = 102400; kt = s - 25; }
  const int k0 = kt * 16;
#pragma unroll
  for (int i = 0; i < 8; ++i) {                 // 512 thr x 8 = 16 x 256 floats
    const int idx = i * 512 + tid;
    const int kl = idx >> 8, col = idx & 255;
    const int kg = k0 + kl;
    ldsF[kl][col] = (kg < kmax) ? W[kg * 256 + col] : 0.0f;   // coalesced rows
  }
  __syncthreads();
  const int j = tid >> 6, lane = tid & 63;
  const int col = j * 32 + (lane & 31);
  const int kb = 8 * (lane >> 5);
  i32x4 v = { (int)pk2bf(ldsF[kb + 0][col], ldsF[kb + 1][col]),
              (int)pk2bf(ldsF[kb + 2][col], ldsF[kb + 3][col]),
              (int)pk2bf(ldsF[kb + 4][col], ldsF[kb + 5][col]),
              (int)pk2bf(ldsF[kb + 6][col], ldsF[kb + 7][col]) };
  *(i32x4*)(packW + base + (kt * 8 + j) * 512 + lane * 8) = v;
}

// ---------------- one GCN layer, ONE phase (all 256 cols per wave) ----------------
// Node map: A-row m holds node 32w + sig(m); C/D reg r of lane (q,c) = node 32w+16q+r.
// acc[j] covers cols 32j + c. One boundary exchange (epoch e) per LAYER.
template <int KT, int LAYER>
__device__ __forceinline__ void gcn_layer(
    const int w, const int lane, const int q, const int c, const int sig,
    const int wp, const int wn, const int e,
    const unsigned short* __restrict__ packL,
    const float* __restrict__ BIAS,
    const bf16x8* Aold, bf16x8* Anew,
    unsigned short* bndE, unsigned int* flagsL,
    unsigned int* scr3_w, float* poolw) {
  const float T = 0.33333333333f;
  f32x16 acc[8];
#pragma unroll
  for (int j = 0; j < 8; ++j)
#pragma unroll
    for (int i = 0; i < 16; ++i) acc[j][i] = 0.f;

  // K-loop: KT x 8 = up to 128 MFMAs, 8 independent chains, loads deep-pipelined
  {
    const bf16x8* wb = (const bf16x8*)packL;
#pragma unroll
    for (int kt = 0; kt < KT; ++kt) {
#pragma unroll
      for (int j = 0; j < 8; ++j) {
        bf16x8 bf = wb[(kt * 8 + j) * 64 + lane];
        acc[j] = __builtin_amdgcn_mfma_f32_32x32x16_bf16(Aold[kt], bf, acc[j], 0, 0, 0);
      }
    }
  }

  // publish boundary nodes (32w @ q0 reg0, 32w+31 @ q1 reg15), all 256 cols, then flag
  {
    unsigned short* myb = bndE + (e * 8 + w) * 512;
    if (q == 0) {
#pragma unroll
      for (int j = 0; j < 8; ++j) myb[j * 32 + c] = f2bf(acc[j][0]);
    } else {
#pragma unroll
      for (int j = 0; j < 8; ++j) myb[256 + j * 32 + c] = f2bf(acc[j][15]);
    }
    if (lane == 0)
      __hip_atomic_store(&flagsL[e * 8 + w], 1u, __ATOMIC_RELEASE,
                         __HIP_MEMORY_SCOPE_WORKGROUP);
  }
  // wait only on the two neighbor waves (dataflow, no barrier)
#pragma clang loop unroll(disable)
  while (__hip_atomic_load(&flagsL[e * 8 + wp], __ATOMIC_ACQUIRE,
                           __HIP_MEMORY_SCOPE_WORKGROUP) == 0u)
    __builtin_amdgcn_s_sleep(1);
#pragma clang loop unroll(disable)
  while (__hip_atomic_load(&flagsL[e * 8 + wn], __ATOMIC_ACQUIRE,
                           __HIP_MEMORY_SCOPE_WORKGROUP) == 0u)
    __builtin_amdgcn_s_sleep(1);

  const unsigned short* pb = bndE + (e * 8 + wp) * 512 + 256;  // node 32w-1 row
  const unsigned short* nb = bndE + (e * 8 + wn) * 512;        // node 32w+32 row

  // epilogue: 4 chunks of 64 cols (tiles 2cg, 2cg+1): 3-tap + bias + silu,
  // then transpose -> next-layer A-frags (same-wave DS, in-order) or pool.
#pragma unroll
  for (int cg = 0; cg < 4; ++cg) {
    const int j0 = 2 * cg, j1 = 2 * cg + 1;
    const float e0t0  = __shfl_xor(acc[j0][0], 32);
    const float e0t1  = __shfl_xor(acc[j1][0], 32);
    const float e15t0 = __shfl_xor(acc[j0][15], 32);
    const float e15t1 = __shfl_xor(acc[j1][15], 32);
    const float bp0 = bf2f(pb[j0 * 32 + c]);
    const float bp1 = bf2f(pb[j1 * 32 + c]);
    const float bn0 = bf2f(nb[j0 * 32 + c]);
    const float bn1 = bf2f(nb[j1 * 32 + c]);
    const float bias0 = BIAS[j0 * 32 + c], bias1 = BIAS[j1 * 32 + c];
    float ps0 = 0.f, ps1 = 0.f;
#pragma unroll
    for (int r = 0; r < 16; ++r) {
      float pr0, pr1, nx0, nx1;
      if (r > 0)  { pr0 = acc[j0][r - 1]; pr1 = acc[j1][r - 1]; }
      else        { pr0 = q ? e15t0 : bp0; pr1 = q ? e15t1 : bp1; }
      if (r < 15) { nx0 = acc[j0][r + 1]; nx1 = acc[j1][r + 1]; }
      else        { nx0 = q ? bn0 : e0t0; nx1 = q ? bn1 : e0t1; }
      const float v0 = (pr0 + acc[j0][r] + nx0) * T + bias0;
      const float v1 = (pr1 + acc[j1][r] + nx1) * T + bias1;
      const float y0 = silu_f(v0);
      const float y1 = silu_f(v1);
      if constexpr (LAYER == 2) { ps0 += y0; ps1 += y1; }
      else scr3_w[(16 * q + r) * 34 + c] = pk2bf(y0, y1);   // row = node-local idx
    }
    if constexpr (LAYER == 2) {
      float s0 = ps0 + __shfl_xor(ps0, 32);
      float s1 = ps1 + __shfl_xor(ps1, 32);
      if (q == 0) { poolw[w * 256 + cg * 64 + c]      = s0;
                    poolw[w * 256 + cg * 64 + 32 + c] = s1; }
    } else {
      const unsigned int* sb = scr3_w + sig * 34;
      uint2 d0 = *(const uint2*)(sb + 8 * q + 0);
      uint2 d1 = *(const uint2*)(sb + 8 * q + 2);
      uint2 d2 = *(const uint2*)(sb + 8 * q + 4);
      uint2 d3 = *(const uint2*)(sb + 8 * q + 6);
      uint2 e0 = *(const uint2*)(sb + 16 + 8 * q + 0);
      uint2 e1 = *(const uint2*)(sb + 16 + 8 * q + 2);
      uint2 e2 = *(const uint2*)(sb + 16 + 8 * q + 4);
      uint2 e3 = *(const uint2*)(sb + 16 + 8 * q + 6);
      i32x4 f0 = { (int)lo_pack(d0.x, d0.y), (int)lo_pack(d1.x, d1.y),
                   (int)lo_pack(d2.x, d2.y), (int)lo_pack(d3.x, d3.y) };
      i32x4 f1 = { (int)lo_pack(e0.x, e0.y), (int)lo_pack(e1.x, e1.y),
                   (int)lo_pack(e2.x, e2.y), (int)lo_pack(e3.x, e3.y) };
      i32x4 f2v = { (int)hi_pack(d0.x, d0.y), (int)hi_pack(d1.x, d1.y),
                    (int)hi_pack(d2.x, d2.y), (int)hi_pack(d3.x, d3.y) };
      i32x4 f3 = { (int)hi_pack(e0.x, e0.y), (int)hi_pack(e1.x, e1.y),
                   (int)hi_pack(e2.x, e2.y), (int)hi_pack(e3.x, e3.y) };
      Anew[cg * 4 + 0] = __builtin_bit_cast(bf16x8, f0);
      Anew[cg * 4 + 1] = __builtin_bit_cast(bf16x8, f1);
      Anew[cg * 4 + 2] = __builtin_bit_cast(bf16x8, f2v);
      Anew[cg * 4 + 3] = __builtin_bit_cast(bf16x8, f3);
    }
  }
}

// ---------------- main fused kernel: 1 block = 1 graph, 8 waves x 32 nodes ----------
__global__ __launch_bounds__(512, 2) void poly_kernel(
    const float* __restrict__ x, const float* __restrict__ t,
    const float* __restrict__ tw, const float* __restrict__ tb,
    const unsigned short* __restrict__ packW,
    const float* __restrict__ B0, const float* __restrict__ B1,
    const float* __restrict__ B2, float* __restrict__ out) {
  __shared__ __align__(16) unsigned short bndE[12288];   // 24 KiB: 3 epochs x 8 w x 512
  __shared__ unsigned int flagsL[24];                    // per-(epoch,wave) flags
  __shared__ __align__(16) unsigned int   scr3[8 * 1088];// 34 KiB per-wave transpose
  __shared__ __align__(16) unsigned short temb_sh[160];  // padded time embedding (bf16)
  // pool partials overlay epoch-0 bnd slots: wave w writes slot w only AFTER waves
  // w+-1 passed their epoch-1 spin, which required them to have consumed epoch-0.
  float* poolL = (float*)bndE;                           // 2048 floats = epoch-0 region

  const int tid = threadIdx.x;
  const int w = tid >> 6, lane = tid & 63;
  const int q = lane >> 5, c = lane & 31;
  const int wp = (w + 7) & 7, wn = (w + 1) & 7;
  const int b = blockIdx.x;
  const int sig = (c & 3) + 4 * ((c >> 3) & 3) + 16 * ((c >> 2) & 1);

  // zero this wave's 3 epoch flags (published by the MLP's first barrier)
  if (lane < 3) flagsL[lane * 8 + w] = 0;

  // ---- fused time MLP: temb = silu(sinemb(t[b]) @ tw + tb), padded [0x6, ., 0x10] ----
  {
    float* e_sh = (float*)(bndE + 4096); // 128 floats scratch (epoch-1 region, free now)
    float* part = (float*)scr3;          // 512 float partials
    if (tid < 128) {
      const float tv = t[b];
      const int i = tid & 63;
      const float f = expf(-0.14619588396823767f * (float)i);  // log(1e4)/63
      const float ang = tv * f;
      e_sh[tid] = (tid < 64) ? sinf(ang) : cosf(ang);
    }
    __syncthreads();
    {
      const int j = tid & 127, p = tid >> 7;   // 4-way k-split over the block
      float a = 0.f;
#pragma unroll 8
      for (int kk = 0; kk < 32; ++kk) {
        const int k = p * 32 + kk;
        a += e_sh[k] * tw[k * 128 + j];
      }
      part[tid] = a;
    }
    __syncthreads();
    if (tid < 128) {
      const float a = tb[tid] + part[tid] + part[128 + tid] + part[256 + tid] + part[384 + tid];
      temb_sh[6 + tid] = f2bf(silu_f(a));
      if (tid < 6)  temb_sh[tid] = 0;
      if (tid < 10) temb_sh[134 + tid] = 0;
    }
    __syncthreads();   // temb + zeroed flags visible to all waves
  }

  // layer-0 A frags: [coords(2), pe(4), temb(128), pad0(10)] = K 144
  bf16x8 A0[9], A1[16];
  {
#pragma unroll
    for (int kt = 0; kt < 9; ++kt)
      A0[kt] = *(const bf16x8*)(temb_sh + kt * 16 + q * 8);
    if (q == 0) {  // k=0..5 live in q==0 lanes of k-tile 0; A-row m=c holds node 32w+sig
      const int n = w * 32 + sig;
      const float2 xy = ((const float2*)x)[b * 256 + n];
      const float th = 0.024543692605870074f * (float)n;   // 2*pi/256
      A0[0][0] = (short)f2bf(xy.x);
      A0[0][1] = (short)f2bf(xy.y);
      A0[0][2] = (short)f2bf(sinf(th));
      A0[0][3] = (short)f2bf(cosf(th));
      A0[0][4] = (short)f2bf(sinf(2.f * th));
      A0[0][5] = (short)f2bf(cosf(2.f * th));
    }
  }

  unsigned int* scr3_w = scr3 + w * 1088;
  gcn_layer< 9, 0>(w, lane, q, c, sig, wp, wn, 0, packW,          B0, A0, A1,
                   bndE, flagsL, scr3_w, poolL);
  gcn_layer<16, 1>(w, lane, q, c, sig, wp, wn, 1, packW + 36864,  B1, A1, A1,  // in place
                   bndE, flagsL, scr3_w, poolL);
  gcn_layer<16, 2>(w, lane, q, c, sig, wp, wn, 2, packW + 102400, B2, A1, A1,
                   bndE, flagsL, scr3_w, poolL);

  __syncthreads();   // the single closing barrier before the pooled reduction
  if (tid < 256) {
    float s = 0.f;
#pragma unroll
    for (int ww = 0; ww < 8; ++ww) s += poolL[ww * 256 + tid];
    out[b * 256 + tid] = s * (1.f / 256.f);
  }
}

// ---------------- launch ----------------
extern "C" void kernel_launch(void* const* d_in, const int* in_sizes, int n_in,
                              void* d_out, int out_size, void* d_ws, size_t ws_size,
                              hipStream_t stream) {
  const float* x  = (const float*)d_in[0];
  const float* t  = (const float*)d_in[1];
  const float* tw = (const float*)d_in[2];
  const float* tb = (const float*)d_in[3];
  const float* W0 = (const float*)d_in[4];
  const float* b0 = (const float*)d_in[5];
  const float* W1 = (const float*)d_in[6];
  const float* b1 = (const float*)d_in[7];
  const float* W2 = (const float*)d_in[8];
  const float* b2 = (const float*)d_in[9];

  unsigned short* packW = (unsigned short*)d_ws;   // 167936 shorts
  float* out = (float*)d_out;

  pack_kernel<<<41, 512, 0, stream>>>(W0, W1, W2, packW);
  poly_kernel<<<1024, 512, 0, stream>>>(x, t, tw, tb, packW, b0, b1, b2, out);
}

// Round 10
// 208.122 us; speedup vs baseline: 1.5368x; 1.5368x over previous
//
#include <hip/hip_runtime.h>
#include <cstdint>

typedef __attribute__((ext_vector_type(8)))  short bf16x8;   // 8 x bf16 (4 VGPR)
typedef __attribute__((ext_vector_type(16))) float f32x16;   // MFMA 32x32 acc
typedef __attribute__((ext_vector_type(2)))  float f32x2;
typedef __attribute__((ext_vector_type(4)))  int   i32x4;

__device__ __forceinline__ unsigned short f2bf(float x) {    // RNE fp32->bf16
  unsigned u = __float_as_uint(x);
  u += 0x7fffu + ((u >> 16) & 1u);
  return (unsigned short)(u >> 16);
}
__device__ __forceinline__ float bf2f(unsigned short h) {
  return __uint_as_float(((unsigned)h) << 16);
}
__device__ __forceinline__ unsigned pk2bf(float lo, float hi) {
#if defined(__has_builtin)
#if __has_builtin(__builtin_amdgcn_cvt_pk_bf16_f32)
  auto v = __builtin_amdgcn_cvt_pk_bf16_f32(lo, hi);
  unsigned u; __builtin_memcpy(&u, &v, 4); return u;
#else
  return ((unsigned)f2bf(hi) << 16) | (unsigned)f2bf(lo);
#endif
#else
  return ((unsigned)f2bf(hi) << 16) | (unsigned)f2bf(lo);
#endif
}
__device__ __forceinline__ float exp2_f(float x) {           // 2^x via v_exp_f32
#if defined(__has_builtin)
#if __has_builtin(__builtin_amdgcn_exp2f)
  return __builtin_amdgcn_exp2f(x);
#else
  return __builtin_exp2f(x);
#endif
#else
  return __builtin_exp2f(x);
#endif
}
__device__ __forceinline__ float silu_f(float v) {
  return v * __builtin_amdgcn_rcpf(1.0f + __expf(-v));
}
__device__ __forceinline__ unsigned lo_pack(unsigned x, unsigned y) {
  return __builtin_amdgcn_perm(y, x, 0x05040100u);   // x.lo16 | y.lo16<<16
}
__device__ __forceinline__ unsigned hi_pack(unsigned x, unsigned y) {
  return __builtin_amdgcn_perm(y, x, 0x07060302u);
}

// ---- pack W0/W1/W2 into MFMA B-frag order via LDS transpose (coalesced R+W).
// dest layout: [layer][g(64 cols)][t(32-col tile)][kt][lane][8], K0 padded 134->144.
__global__ void pack_kernel(const float* __restrict__ W0, const float* __restrict__ W1,
                            const float* __restrict__ W2,
                            unsigned short* __restrict__ packW) {
  __shared__ float ldsF[16][257];
  const int s = blockIdx.x, tid = threadIdx.x;
  const float* W; int KT, kmax, base, kt;
  if (s < 9)       { W = W0; KT = 9;  kmax = 134; base = 0;      kt = s; }
  else if (s < 25) { W = W1; KT = 16; kmax = 256; base = 36864;  kt = s - 9; }
  else             { W = W2; KT = 16; kmax = 256; base = 102400; kt = s - 25; }
  const int k0 = kt * 16;
#pragma unroll
  for (int i = 0; i < 8; ++i) {                 // 512 thr x 8 = 16 x 256 floats
    const int idx = i * 512 + tid;
    const int kl = idx >> 8, col = idx & 255;
    const int kg = k0 + kl;
    ldsF[kl][col] = (kg < kmax) ? W[kg * 256 + col] : 0.0f;   // coalesced rows
  }
  __syncthreads();
  const int g = tid >> 7, t = (tid >> 6) & 1, lane = tid & 63;
  const int col = g * 64 + t * 32 + (lane & 31);
  const int kb = 8 * (lane >> 5);
  unsigned u0 = pk2bf(ldsF[kb + 0][col], ldsF[kb + 1][col]);
  unsigned u1 = pk2bf(ldsF[kb + 2][col], ldsF[kb + 3][col]);
  unsigned u2 = pk2bf(ldsF[kb + 4][col], ldsF[kb + 5][col]);
  unsigned u3 = pk2bf(ldsF[kb + 6][col], ldsF[kb + 7][col]);
  unsigned short* dst = packW + base + g * (KT * 1024) + t * (KT * 512) + kt * 512 + lane * 8;
  i32x4 v = { (int)u0, (int)u1, (int)u2, (int)u3 };
  *(i32x4*)dst = v;
}

// ---------------- one GCN layer (R4 structure + pk-f32 epilogue) ----------------
// Node map: A-row m holds node 32w + sig(m), sig(m)=(m&3)+4((m>>3)&3)+16((m>>2)&1)
// => C/D reg r of lane (q,c) = node 32w + 16q + r.
// Per group: both B tiles streamed from global (L1-resident 32KB group slab),
// one __syncthreads per group, bnd parity double-buffer (packed b32 entries).
template <int KT, int LAYER>
__device__ __forceinline__ void gcn_layer(
    const int w, const int lane, const int q, const int c, const int sig,
    const unsigned short* __restrict__ packL,
    const float* __restrict__ BIAS,
    const bf16x8* Aold, bf16x8* Anew,
    unsigned int* bndu, unsigned int* scr3_w, float* poolw) {
  const float T  = 0.33333333333f;
  const float L2E = 1.44269504f;     // log2(e)
  const float NL2 = -0.69314718f;    // -ln2

  // prefetch kt=0 B pair of group 0 (warm start)
  bf16x8 pf0 = ((const bf16x8*)packL)[lane];
  bf16x8 pf1 = ((const bf16x8*)(packL + KT * 512))[lane];

#pragma unroll
  for (int g = 0; g < 4; ++g) {
    const unsigned short* srcg = packL + g * (KT * 1024);
    f32x16 acc0, acc1;
#pragma unroll
    for (int i = 0; i < 16; ++i) { acc0[i] = 0.f; acc1[i] = 0.f; }
    {
      const bf16x8* wb0 = (const bf16x8*)srcg;
      const bf16x8* wb1 = (const bf16x8*)(srcg + KT * 512);
      acc0 = __builtin_amdgcn_mfma_f32_32x32x16_bf16(Aold[0], pf0, acc0, 0, 0, 0);
      acc1 = __builtin_amdgcn_mfma_f32_32x32x16_bf16(Aold[0], pf1, acc1, 0, 0, 0);
#pragma unroll
      for (int kt = 1; kt < KT; ++kt) {
        bf16x8 b0 = wb0[kt * 64 + lane];
        bf16x8 b1 = wb1[kt * 64 + lane];
        acc0 = __builtin_amdgcn_mfma_f32_32x32x16_bf16(Aold[kt], b0, acc0, 0, 0, 0);
        acc1 = __builtin_amdgcn_mfma_f32_32x32x16_bf16(Aold[kt], b1, acc1, 0, 0, 0);
      }
    }

    // prefetch next group's kt=0 pair (completes across the barrier drain)
    if (g < 3) {
      const unsigned short* nxt = packL + (g + 1) * (KT * 1024);
      pf0 = ((const bf16x8*)nxt)[lane];
      pf1 = ((const bf16x8*)(nxt + KT * 512))[lane];
    }

    // publish wave-boundary nodes, packed (tile0, tile1) in one dword
    unsigned int* bndp = bndu + (g & 1) * 1024;
    if (q == 0) bndp[(w * 2 + 0) * 32 + c] = pk2bf(acc0[0],  acc1[0]);
    else        bndp[(w * 2 + 1) * 32 + c] = pk2bf(acc0[15], acc1[15]);
    __syncthreads();   // single per-group barrier: bnd(g) visible (+vmcnt drain)

    // cross-half edge values (node 15 <-> 16 of the wave's 32-node stripe)
    const float e0t0  = __shfl_xor(acc0[0], 32);
    const float e0t1  = __shfl_xor(acc1[0], 32);
    const float e15t0 = __shfl_xor(acc0[15], 32);
    const float e15t1 = __shfl_xor(acc1[15], 32);
    const unsigned pbu = bndp[(((w + 7) & 7) * 2 + 1) * 32 + c];   // node 32w-1
    const unsigned nbu = bndp[(((w + 1) & 7) * 2 + 0) * 32 + c];   // node 32w+32
    const float bp0 = bf2f((unsigned short)(pbu & 0xffff));
    const float bp1 = bf2f((unsigned short)(pbu >> 16));
    const float bn0 = bf2f((unsigned short)(nbu & 0xffff));
    const float bn1 = bf2f((unsigned short)(nbu >> 16));
    const float bias0 = BIAS[g * 64 + c], bias1 = BIAS[g * 64 + 32 + c];
    // silu(v) with v = s*T + bias, computed as: n = s*(-L2E*T) + (-L2E*bias);
    // e = 2^n = exp(-v); v = n*(-ln2); y = v * rcp(1+e).  All pairwise (v_pk_*).
    f32x2 cT2;  cT2.x = -L2E * T;      cT2.y = -L2E * T;
    f32x2 nb2;  nb2.x = -L2E * bias0;  nb2.y = -L2E * bias1;
    f32x2 ps2;  ps2.x = 0.f;           ps2.y = 0.f;
#pragma unroll
    for (int r = 0; r < 16; ++r) {
      f32x2 pr2, nx2, ac2;
      if (r > 0)  { pr2.x = acc0[r - 1]; pr2.y = acc1[r - 1]; }
      else        { pr2.x = q ? e15t0 : bp0; pr2.y = q ? e15t1 : bp1; }
      if (r < 15) { nx2.x = acc0[r + 1]; nx2.y = acc1[r + 1]; }
      else        { nx2.x = q ? bn0 : e0t0; nx2.y = q ? bn1 : e0t1; }
      ac2.x = acc0[r]; ac2.y = acc1[r];
      f32x2 s2 = (pr2 + ac2) + nx2;            // 2x v_pk_add_f32
      f32x2 n2 = s2 * cT2 + nb2;               // v_pk_fma_f32
      f32x2 v2 = n2 * NL2;                     // v_pk_mul_f32
      f32x2 e2; e2.x = exp2_f(n2.x); e2.y = exp2_f(n2.y);
      f32x2 d2 = e2 + 1.0f;                    // v_pk_add_f32
      f32x2 r2; r2.x = __builtin_amdgcn_rcpf(d2.x); r2.y = __builtin_amdgcn_rcpf(d2.y);
      f32x2 y2 = v2 * r2;                      // v_pk_mul_f32
      if constexpr (LAYER == 2) { ps2 += y2; }
      else scr3_w[(16 * q + r) * 34 + c] = pk2bf(y2.x, y2.y);  // row = node-local idx
    }

    if constexpr (LAYER == 2) {
      float s0 = ps2.x + __shfl_xor(ps2.x, 32);
      float s1 = ps2.y + __shfl_xor(ps2.y, 32);
      if (q == 0) { poolw[w * 256 + g * 64 + c]      = s0;
                    poolw[w * 256 + g * 64 + 32 + c] = s1; }
    } else {
      // rebuild next-layer A-frags (same-wave DS, in-order -> no barrier);
      // A-row m=c needs node-local sig(c)
      const unsigned int* sb = scr3_w + sig * 34;
      uint2 d0 = *(const uint2*)(sb + 8 * q + 0);
      uint2 d1 = *(const uint2*)(sb + 8 * q + 2);
      uint2 d2 = *(const uint2*)(sb + 8 * q + 4);
      uint2 d3 = *(const uint2*)(sb + 8 * q + 6);
      uint2 e0 = *(const uint2*)(sb + 16 + 8 * q + 0);
      uint2 e1 = *(const uint2*)(sb + 16 + 8 * q + 2);
      uint2 e2 = *(const uint2*)(sb + 16 + 8 * q + 4);
      uint2 e3 = *(const uint2*)(sb + 16 + 8 * q + 6);
      i32x4 f0 = { (int)lo_pack(d0.x, d0.y), (int)lo_pack(d1.x, d1.y),
                   (int)lo_pack(d2.x, d2.y), (int)lo_pack(d3.x, d3.y) };
      i32x4 f1 = { (int)lo_pack(e0.x, e0.y), (int)lo_pack(e1.x, e1.y),
                   (int)lo_pack(e2.x, e2.y), (int)lo_pack(e3.x, e3.y) };
      i32x4 f2v = { (int)hi_pack(d0.x, d0.y), (int)hi_pack(d1.x, d1.y),
                    (int)hi_pack(d2.x, d2.y), (int)hi_pack(d3.x, d3.y) };
      i32x4 f3 = { (int)hi_pack(e0.x, e0.y), (int)hi_pack(e1.x, e1.y),
                   (int)hi_pack(e2.x, e2.y), (int)hi_pack(e3.x, e3.y) };
      Anew[g * 4 + 0] = __builtin_bit_cast(bf16x8, f0);
      Anew[g * 4 + 1] = __builtin_bit_cast(bf16x8, f1);
      Anew[g * 4 + 2] = __builtin_bit_cast(bf16x8, f2v);
      Anew[g * 4 + 3] = __builtin_bit_cast(bf16x8, f3);
    }
  }
}

// ---------------- main fused kernel: 1 block = 1 graph, 8 waves x 32 nodes ----------
__global__ __launch_bounds__(512, 2) void poly_kernel(
    const float* __restrict__ x, const float* __restrict__ t,
    const float* __restrict__ tw, const float* __restrict__ tb,
    const unsigned short* __restrict__ packW,
    const float* __restrict__ B0, const float* __restrict__ B1,
    const float* __restrict__ B2, float* __restrict__ out) {
  __shared__ __align__(16) unsigned int   bndu[2048];      //  8 KiB boundary (2 par x 8w x 2 x 32 dwords)
  __shared__ __align__(16) unsigned int   scr3[8 * 1088];  // 34 KiB per-wave packed transpose
  __shared__ __align__(16) unsigned short temb_sh[160];    // padded time embedding (bf16)

  const int tid = threadIdx.x;
  const int w = tid >> 6, lane = tid & 63;
  const int q = lane >> 5, c = lane & 31;
  const int b = blockIdx.x;
  const int sig = (c & 3) + 4 * ((c >> 3) & 3) + 16 * ((c >> 2) & 1);

  // ---- fused time MLP: temb = silu(sinemb(t[b]) @ tw + tb), padded [0x6, ., 0x10] ----
  {
    float* e_sh = (float*)bndu;       // 128 floats
    float* part = (float*)scr3;       // 512 float partials
    if (tid < 128) {
      const float tv = t[b];
      const int i = tid & 63;
      const float f = expf(-0.14619588396823767f * (float)i);  // log(1e4)/63
      const float ang = tv * f;
      e_sh[tid] = (tid < 64) ? sinf(ang) : cosf(ang);
    }
    __syncthreads();
    {
      const int j = tid & 127, p = tid >> 7;   // 4-way k-split over the block
      float a = 0.f;
#pragma unroll 8
      for (int kk = 0; kk < 32; ++kk) {
        const int k = p * 32 + kk;
        a += e_sh[k] * tw[k * 128 + j];
      }
      part[tid] = a;
    }
    __syncthreads();
    if (tid < 128) {
      const float a = tb[tid] + part[tid] + part[128 + tid] + part[256 + tid] + part[384 + tid];
      temb_sh[6 + tid] = f2bf(silu_f(a));
      if (tid < 6)  temb_sh[tid] = 0;
      if (tid < 10) temb_sh[134 + tid] = 0;
    }
    __syncthreads();
  }

  // layer-0 A frags: [coords(2), pe(4), temb(128), pad0(10)] = K 144
  bf16x8 A0[9], A1[16], A2[16];
  {
#pragma unroll
    for (int kt = 0; kt < 9; ++kt)
      A0[kt] = *(const bf16x8*)(temb_sh + kt * 16 + q * 8);
    if (q == 0) {  // k=0..5 live in q==0 lanes of k-tile 0; A-row m=c holds node 32w+sig
      const int n = w * 32 + sig;
      const float2 xy = ((const float2*)x)[b * 256 + n];
      const float th = 0.024543692605870074f * (float)n;   // 2*pi/256
      A0[0][0] = (short)f2bf(xy.x);
      A0[0][1] = (short)f2bf(xy.y);
      A0[0][2] = (short)f2bf(sinf(th));
      A0[0][3] = (short)f2bf(cosf(th));
      A0[0][4] = (short)f2bf(sinf(2.f * th));
      A0[0][5] = (short)f2bf(cosf(2.f * th));
    }
  }

  unsigned int* scr3_w = scr3 + w * 1088;
  float* poolw = (float*)scr3;   // layer-2 per-wave pool partials (transpose dead by then)
  gcn_layer< 9, 0>(w, lane, q, c, sig, packW,          B0, A0, A1, bndu, scr3_w, poolw);
  gcn_layer<16, 1>(w, lane, q, c, sig, packW + 36864,  B1, A1, A2, bndu, scr3_w, poolw);
  gcn_layer<16, 2>(w, lane, q, c, sig, packW + 102400, B2, A2, A1, bndu, scr3_w, poolw);

  __syncthreads();
  if (tid < 256) {
    float s = 0.f;
#pragma unroll
    for (int ww = 0; ww < 8; ++ww) s += poolw[ww * 256 + tid];
    out[b * 256 + tid] = s * (1.f / 256.f);
  }
}

// ---------------- launch ----------------
extern "C" void kernel_launch(void* const* d_in, const int* in_sizes, int n_in,
                              void* d_out, int out_size, void* d_ws, size_t ws_size,
                              hipStream_t stream) {
  const float* x  = (const float*)d_in[0];
  const float* t  = (const float*)d_in[1];
  const float* tw = (const float*)d_in[2];
  const float* tb = (const float*)d_in[3];
  const float* W0 = (const float*)d_in[4];
  const float* b0 = (const float*)d_in[5];
  const float* W1 = (const float*)d_in[6];
  const float* b1 = (const float*)d_in[7];
  const float* W2 = (const float*)d_in[8];
  const float* b2 = (const float*)d_in[9];

  unsigned short* packW = (unsigned short*)d_ws;   // 167936 shorts
  float* out = (float*)d_out;

  pack_kernel<<<41, 512, 0, stream>>>(W0, W1, W2, packW);
  poly_kernel<<<1024, 512, 0, stream>>>(x, t, tw, tb, packW, b0, b1, b2, out);
}

// Round 11
// 205.006 us; speedup vs baseline: 1.5602x; 1.0152x over previous
//
#include <hip/hip_runtime.h>
#include <cstdint>

typedef __attribute__((ext_vector_type(8)))  short bf16x8;   // 8 x bf16 (4 VGPR)
typedef __attribute__((ext_vector_type(16))) float f32x16;   // MFMA 32x32 acc
typedef __attribute__((ext_vector_type(2)))  float f32x2;
typedef __attribute__((ext_vector_type(4)))  int   i32x4;

__device__ __forceinline__ unsigned short f2bf(float x) {    // RNE fp32->bf16
  unsigned u = __float_as_uint(x);
  u += 0x7fffu + ((u >> 16) & 1u);
  return (unsigned short)(u >> 16);
}
__device__ __forceinline__ float bf2f(unsigned short h) {
  return __uint_as_float(((unsigned)h) << 16);
}
__device__ __forceinline__ unsigned pk2bf(float lo, float hi) {
#if defined(__has_builtin)
#if __has_builtin(__builtin_amdgcn_cvt_pk_bf16_f32)
  auto v = __builtin_amdgcn_cvt_pk_bf16_f32(lo, hi);
  unsigned u; __builtin_memcpy(&u, &v, 4); return u;
#else
  return ((unsigned)f2bf(hi) << 16) | (unsigned)f2bf(lo);
#endif
#else
  return ((unsigned)f2bf(hi) << 16) | (unsigned)f2bf(lo);
#endif
}
__device__ __forceinline__ float exp2_f(float x) {
#if defined(__has_builtin)
#if __has_builtin(__builtin_amdgcn_exp2f)
  return __builtin_amdgcn_exp2f(x);
#else
  return __builtin_exp2f(x);
#endif
#else
  return __builtin_exp2f(x);
#endif
}
__device__ __forceinline__ float silu_f(float v) {
  return v * __builtin_amdgcn_rcpf(1.0f + __expf(-v));
}
__device__ __forceinline__ unsigned lo_pack(unsigned x, unsigned y) {
  return __builtin_amdgcn_perm(y, x, 0x05040100u);   // x.lo16 | y.lo16<<16
}
__device__ __forceinline__ unsigned hi_pack(unsigned x, unsigned y) {
  return __builtin_amdgcn_perm(y, x, 0x07060302u);
}

// ---- pack kernel ----
// L0 (rank-1 reduced): only k-tile 0 B-frags (rows 0..5 = W0[0:6], rows 6..15 zero),
//   layout [tile j(8 x 32cols)][lane][8] = 4096 shorts at offset 0.
//   Also emits W0mid bf16 (rows 6..133, [k][col]) at offset 135168 (32768 shorts).
// L1/L2: [g][t][kt][lane][8] as before; L1 base 4096, L2 base 69632.
__global__ void pack_kernel(const float* __restrict__ W0, const float* __restrict__ W1,
                            const float* __restrict__ W2,
                            unsigned short* __restrict__ packW) {
  __shared__ float ldsF[16][257];
  const int s = blockIdx.x, tid = threadIdx.x;
  if (s == 0) {   // ---- layer 0 ----
#pragma unroll
    for (int i = 0; i < 8; ++i) {
      const int idx = i * 512 + tid;
      const int kl = idx >> 8, col = idx & 255;
      ldsF[kl][col] = (kl < 6) ? W0[kl * 256 + col] : 0.0f;
    }
    __syncthreads();
    {
      const int j = tid >> 6, lane = tid & 63;
      const int col = j * 32 + (lane & 31);
      const int kb = 8 * (lane >> 5);
      i32x4 v = { (int)pk2bf(ldsF[kb + 0][col], ldsF[kb + 1][col]),
                  (int)pk2bf(ldsF[kb + 2][col], ldsF[kb + 3][col]),
                  (int)pk2bf(ldsF[kb + 4][col], ldsF[kb + 5][col]),
                  (int)pk2bf(ldsF[kb + 6][col], ldsF[kb + 7][col]) };
      *(i32x4*)(packW + j * 512 + lane * 8) = v;
    }
    // W0mid bf16: rows 6..133 -> [k][col], coalesced
    unsigned short* pw0m = packW + 135168;
#pragma unroll
    for (int it = 0; it < 64; ++it) {
      const int idx = it * 512 + tid;
      const int k = idx >> 8, col = idx & 255;
      pw0m[k * 256 + col] = f2bf(W0[(6 + k) * 256 + col]);
    }
    return;
  }
  // ---- L1 / L2 ----
  const float* W; int base, kt;
  if (s <= 16) { W = W1; base = 4096;  kt = s - 1; }
  else         { W = W2; base = 69632; kt = s - 17; }
  const int k0 = kt * 16;
#pragma unroll
  for (int i = 0; i < 8; ++i) {
    const int idx = i * 512 + tid;
    const int kl = idx >> 8, col = idx & 255;
    ldsF[kl][col] = W[(k0 + kl) * 256 + col];
  }
  __syncthreads();
  const int g = tid >> 7, t = (tid >> 6) & 1, lane = tid & 63;
  const int col = g * 64 + t * 32 + (lane & 31);
  const int kb = 8 * (lane >> 5);
  i32x4 v = { (int)pk2bf(ldsF[kb + 0][col], ldsF[kb + 1][col]),
              (int)pk2bf(ldsF[kb + 2][col], ldsF[kb + 3][col]),
              (int)pk2bf(ldsF[kb + 4][col], ldsF[kb + 5][col]),
              (int)pk2bf(ldsF[kb + 6][col], ldsF[kb + 7][col]) };
  *(i32x4*)(packW + base + g * 16384 + t * 8192 + kt * 512 + lane * 8) = v;
}

// ---------------- L1/L2 layer (R10-verified structure) ----------------
template <int KT, int LAYER>
__device__ __forceinline__ void gcn_layer(
    const int w, const int lane, const int q, const int c, const int sig,
    const unsigned short* __restrict__ packL,
    const float* __restrict__ BIAS,
    const bf16x8* Aold, bf16x8* Anew,
    unsigned int* bndu, unsigned int* scr3_w, float* poolw) {
  const float T  = 0.33333333333f;
  const float L2E = 1.44269504f;
  const float NL2 = -0.69314718f;

  bf16x8 pf0 = ((const bf16x8*)packL)[lane];
  bf16x8 pf1 = ((const bf16x8*)(packL + KT * 512))[lane];

#pragma unroll
  for (int g = 0; g < 4; ++g) {
    const unsigned short* srcg = packL + g * (KT * 1024);
    f32x16 acc0, acc1;
#pragma unroll
    for (int i = 0; i < 16; ++i) { acc0[i] = 0.f; acc1[i] = 0.f; }
    {
      const bf16x8* wb0 = (const bf16x8*)srcg;
      const bf16x8* wb1 = (const bf16x8*)(srcg + KT * 512);
      acc0 = __builtin_amdgcn_mfma_f32_32x32x16_bf16(Aold[0], pf0, acc0, 0, 0, 0);
      acc1 = __builtin_amdgcn_mfma_f32_32x32x16_bf16(Aold[0], pf1, acc1, 0, 0, 0);
#pragma unroll
      for (int kt = 1; kt < KT; ++kt) {
        bf16x8 b0 = wb0[kt * 64 + lane];
        bf16x8 b1 = wb1[kt * 64 + lane];
        acc0 = __builtin_amdgcn_mfma_f32_32x32x16_bf16(Aold[kt], b0, acc0, 0, 0, 0);
        acc1 = __builtin_amdgcn_mfma_f32_32x32x16_bf16(Aold[kt], b1, acc1, 0, 0, 0);
      }
    }
    if (g < 3) {
      const unsigned short* nxt = packL + (g + 1) * (KT * 1024);
      pf0 = ((const bf16x8*)nxt)[lane];
      pf1 = ((const bf16x8*)(nxt + KT * 512))[lane];
    }

    unsigned int* bndp = bndu + (g & 1) * 1024;
    if (q == 0) bndp[(w * 2 + 0) * 32 + c] = pk2bf(acc0[0],  acc1[0]);
    else        bndp[(w * 2 + 1) * 32 + c] = pk2bf(acc0[15], acc1[15]);
    __syncthreads();

    const float e0t0  = __shfl_xor(acc0[0], 32);
    const float e0t1  = __shfl_xor(acc1[0], 32);
    const float e15t0 = __shfl_xor(acc0[15], 32);
    const float e15t1 = __shfl_xor(acc1[15], 32);
    const unsigned pbu = bndp[(((w + 7) & 7) * 2 + 1) * 32 + c];
    const unsigned nbu = bndp[(((w + 1) & 7) * 2 + 0) * 32 + c];
    const float bp0 = bf2f((unsigned short)(pbu & 0xffff));
    const float bp1 = bf2f((unsigned short)(pbu >> 16));
    const float bn0 = bf2f((unsigned short)(nbu & 0xffff));
    const float bn1 = bf2f((unsigned short)(nbu >> 16));
    const float bias0 = BIAS[g * 64 + c], bias1 = BIAS[g * 64 + 32 + c];
    f32x2 cT2;  cT2.x = -L2E * T;      cT2.y = -L2E * T;
    f32x2 nb2;  nb2.x = -L2E * bias0;  nb2.y = -L2E * bias1;
    f32x2 ps2;  ps2.x = 0.f;           ps2.y = 0.f;
#pragma unroll
    for (int r = 0; r < 16; ++r) {
      f32x2 pr2, nx2, ac2;
      if (r > 0)  { pr2.x = acc0[r - 1]; pr2.y = acc1[r - 1]; }
      else        { pr2.x = q ? e15t0 : bp0; pr2.y = q ? e15t1 : bp1; }
      if (r < 15) { nx2.x = acc0[r + 1]; nx2.y = acc1[r + 1]; }
      else        { nx2.x = q ? bn0 : e0t0; nx2.y = q ? bn1 : e0t1; }
      ac2.x = acc0[r]; ac2.y = acc1[r];
      f32x2 s2 = (pr2 + ac2) + nx2;
      f32x2 n2 = s2 * cT2 + nb2;
      f32x2 v2 = n2 * NL2;
      f32x2 e2; e2.x = exp2_f(n2.x); e2.y = exp2_f(n2.y);
      f32x2 d2 = e2 + 1.0f;
      f32x2 r2; r2.x = __builtin_amdgcn_rcpf(d2.x); r2.y = __builtin_amdgcn_rcpf(d2.y);
      f32x2 y2 = v2 * r2;
      if constexpr (LAYER == 2) { ps2 += y2; }
      else scr3_w[(16 * q + r) * 34 + c] = pk2bf(y2.x, y2.y);
    }

    if constexpr (LAYER == 2) {
      float s0 = ps2.x + __shfl_xor(ps2.x, 32);
      float s1 = ps2.y + __shfl_xor(ps2.y, 32);
      if (q == 0) { poolw[w * 256 + g * 64 + c]      = s0;
                    poolw[w * 256 + g * 64 + 32 + c] = s1; }
    } else {
      const unsigned int* sb = scr3_w + sig * 34;
      uint2 d0 = *(const uint2*)(sb + 8 * q + 0);
      uint2 d1 = *(const uint2*)(sb + 8 * q + 2);
      uint2 d2 = *(const uint2*)(sb + 8 * q + 4);
      uint2 d3 = *(const uint2*)(sb + 8 * q + 6);
      uint2 e0 = *(const uint2*)(sb + 16 + 8 * q + 0);
      uint2 e1 = *(const uint2*)(sb + 16 + 8 * q + 2);
      uint2 e2 = *(const uint2*)(sb + 16 + 8 * q + 4);
      uint2 e3 = *(const uint2*)(sb + 16 + 8 * q + 6);
      i32x4 f0 = { (int)lo_pack(d0.x, d0.y), (int)lo_pack(d1.x, d1.y),
                   (int)lo_pack(d2.x, d2.y), (int)lo_pack(d3.x, d3.y) };
      i32x4 f1 = { (int)lo_pack(e0.x, e0.y), (int)lo_pack(e1.x, e1.y),
                   (int)lo_pack(e2.x, e2.y), (int)lo_pack(e3.x, e3.y) };
      i32x4 f2v = { (int)hi_pack(d0.x, d0.y), (int)hi_pack(d1.x, d1.y),
                    (int)hi_pack(d2.x, d2.y), (int)hi_pack(d3.x, d3.y) };
      i32x4 f3 = { (int)hi_pack(e0.x, e0.y), (int)hi_pack(e1.x, e1.y),
                   (int)hi_pack(e2.x, e2.y), (int)hi_pack(e3.x, e3.y) };
      Anew[g * 4 + 0] = __builtin_bit_cast(bf16x8, f0);
      Anew[g * 4 + 1] = __builtin_bit_cast(bf16x8, f1);
      Anew[g * 4 + 2] = __builtin_bit_cast(bf16x8, f2v);
      Anew[g * 4 + 3] = __builtin_bit_cast(bf16x8, f3);
    }
  }
}

// ---------------- main fused kernel: 1 block = 1 graph, 8 waves x 32 nodes ----------
__global__ __launch_bounds__(512, 2) void poly_kernel(
    const float* __restrict__ x, const float* __restrict__ t,
    const float* __restrict__ tw, const float* __restrict__ tb,
    const unsigned short* __restrict__ packW,
    const float* __restrict__ B0, const float* __restrict__ B1,
    const float* __restrict__ B2, float* __restrict__ out) {
  __shared__ __align__(16) unsigned int   bndu[2048];      //  8 KiB L1/L2 boundary (parity)
  __shared__ __align__(16) unsigned int   bndL0[2048];     //  8 KiB L0 boundary (+temb overlay)
  __shared__ __align__(16) unsigned int   scr3[8 * 1088];  // 34 KiB per-wave transpose
  __shared__ float biasEff[256];                           //  1 KiB b0 + u (rank-1 temb)

  const int tid = threadIdx.x;
  const int w = tid >> 6, lane = tid & 63;
  const int q = lane >> 5, c = lane & 31;
  const int b = blockIdx.x;
  const int sig = (c & 3) + 4 * ((c >> 3) & 3) + 16 * ((c >> 2) & 1);

  // ---- preamble: temb (fp32) then biasEff = b0 + temb @ W0[6:134] ----
  {
    float* e_sh   = (float*)bndu;     // 128 floats
    float* part   = (float*)scr3;     // 512 float partials
    float* temb_f = (float*)bndL0;    // 128 floats (bf16-rounded values)
    if (tid < 128) {
      const float tv = t[b];
      const int i = tid & 63;
      const float f = expf(-0.14619588396823767f * (float)i);  // log(1e4)/63
      const float ang = tv * f;
      e_sh[tid] = (tid < 64) ? sinf(ang) : cosf(ang);
    }
    __syncthreads();
    {
      const int j = tid & 127, p = tid >> 7;   // 4-way k-split
      float a = 0.f;
#pragma unroll 8
      for (int kk = 0; kk < 32; ++kk) {
        const int k = p * 32 + kk;
        a += e_sh[k] * tw[k * 128 + j];
      }
      part[tid] = a;
    }
    __syncthreads();
    if (tid < 128) {
      const float a = tb[tid] + part[tid] + part[128 + tid] + part[256 + tid] + part[384 + tid];
      temb_f[tid] = bf2f(f2bf(silu_f(a)));    // match MFMA's bf16 A precision
    }
    __syncthreads();
    {
      // u-GEMV: col = tid&255, k-half p = tid>>8 (64 MACs each), W0mid bf16
      const unsigned short* pw0m = packW + 135168;
      const int col = tid & 255, p = tid >> 8;
      float a = 0.f;
#pragma unroll 8
      for (int kk = 0; kk < 64; ++kk) {
        const int k = p * 64 + kk;
        a += temb_f[k] * bf2f(pw0m[k * 256 + col]);
      }
      part[tid] = a;
    }
    __syncthreads();
    if (tid < 256) biasEff[tid] = B0[tid] + part[tid] + part[256 + tid];
    // visibility of biasEff for all waves: covered by L0's post-publish barrier
  }

  // ---- layer 0, single phase: s0 = [x,y,pe] @ W0[0:6]  (K=16 tile, KT=1) ----
  bf16x8 A1[16], A2[16];
  {
    bf16x8 A00 = {};                  // zero; q==0 lanes carry k=0..5
    if (q == 0) {
      const int n = w * 32 + sig;     // A-row m=c holds node 32w+sig
      const float2 xy = ((const float2*)x)[b * 256 + n];
      const float th = 0.024543692605870074f * (float)n;   // 2*pi/256
      A00[0] = (short)f2bf(xy.x);
      A00[1] = (short)f2bf(xy.y);
      A00[2] = (short)f2bf(sinf(th));
      A00[3] = (short)f2bf(cosf(th));
      A00[4] = (short)f2bf(sinf(2.f * th));
      A00[5] = (short)f2bf(cosf(2.f * th));
    }
    f32x16 acc[8];
#pragma unroll
    for (int j = 0; j < 8; ++j)
#pragma unroll
      for (int i = 0; i < 16; ++i) acc[j][i] = 0.f;
    {
      const bf16x8* wb = (const bf16x8*)packW;   // 8 tiles x 64 lanes
#pragma unroll
      for (int j = 0; j < 8; ++j) {
        bf16x8 bf = wb[j * 64 + lane];
        acc[j] = __builtin_amdgcn_mfma_f32_32x32x16_bf16(A00, bf, acc[j], 0, 0, 0);
      }
    }
    // publish boundary nodes for all 256 cols (packed per 64-col chunk)
    {
      unsigned int* myb = bndL0 + (w * 2 + q) * 128;
      const int rr = q ? 15 : 0;
#pragma unroll
      for (int cg = 0; cg < 4; ++cg)
        myb[cg * 32 + c] = pk2bf(acc[2 * cg][rr], acc[2 * cg + 1][rr]);
    }
    __syncthreads();   // L0's single barrier (also publishes biasEff, preamble scr3 free)

    const float T  = 0.33333333333f;
    const float L2E = 1.44269504f;
    const float NL2 = -0.69314718f;
    unsigned int* scr3_w = scr3 + w * 1088;
#pragma unroll
    for (int cg = 0; cg < 4; ++cg) {
      const int j0 = 2 * cg, j1 = 2 * cg + 1;
      const float e0t0  = __shfl_xor(acc[j0][0], 32);
      const float e0t1  = __shfl_xor(acc[j1][0], 32);
      const float e15t0 = __shfl_xor(acc[j0][15], 32);
      const float e15t1 = __shfl_xor(acc[j1][15], 32);
      const unsigned pbu = bndL0[(((w + 7) & 7) * 2 + 1) * 128 + cg * 32 + c];
      const unsigned nbu = bndL0[(((w + 1) & 7) * 2 + 0) * 128 + cg * 32 + c];
      const float bp0 = bf2f((unsigned short)(pbu & 0xffff));
      const float bp1 = bf2f((unsigned short)(pbu >> 16));
      const float bn0 = bf2f((unsigned short)(nbu & 0xffff));
      const float bn1 = bf2f((unsigned short)(nbu >> 16));
      const float bias0 = biasEff[cg * 64 + c], bias1 = biasEff[cg * 64 + 32 + c];
      f32x2 cT2;  cT2.x = -L2E * T;      cT2.y = -L2E * T;
      f32x2 nb2;  nb2.x = -L2E * bias0;  nb2.y = -L2E * bias1;
#pragma unroll
      for (int r = 0; r < 16; ++r) {
        f32x2 pr2, nx2, ac2;
        if (r > 0)  { pr2.x = acc[j0][r - 1]; pr2.y = acc[j1][r - 1]; }
        else        { pr2.x = q ? e15t0 : bp0; pr2.y = q ? e15t1 : bp1; }
        if (r < 15) { nx2.x = acc[j0][r + 1]; nx2.y = acc[j1][r + 1]; }
        else        { nx2.x = q ? bn0 : e0t0; nx2.y = q ? bn1 : e0t1; }
        ac2.x = acc[j0][r]; ac2.y = acc[j1][r];
        f32x2 s2 = (pr2 + ac2) + nx2;
        f32x2 n2 = s2 * cT2 + nb2;
        f32x2 v2 = n2 * NL2;
        f32x2 e2; e2.x = exp2_f(n2.x); e2.y = exp2_f(n2.y);
        f32x2 d2 = e2 + 1.0f;
        f32x2 r2; r2.x = __builtin_amdgcn_rcpf(d2.x); r2.y = __builtin_amdgcn_rcpf(d2.y);
        f32x2 y2 = v2 * r2;
        scr3_w[(16 * q + r) * 34 + c] = pk2bf(y2.x, y2.y);
      }
      const unsigned int* sb = scr3_w + sig * 34;
      uint2 d0 = *(const uint2*)(sb + 8 * q + 0);
      uint2 d1 = *(const uint2*)(sb + 8 * q + 2);
      uint2 d2 = *(const uint2*)(sb + 8 * q + 4);
      uint2 d3 = *(const uint2*)(sb + 8 * q + 6);
      uint2 e0 = *(const uint2*)(sb + 16 + 8 * q + 0);
      uint2 e1 = *(const uint2*)(sb + 16 + 8 * q + 2);
      uint2 e2 = *(const uint2*)(sb + 16 + 8 * q + 4);
      uint2 e3 = *(const uint2*)(sb + 16 + 8 * q + 6);
      i32x4 f0 = { (int)lo_pack(d0.x, d0.y), (int)lo_pack(d1.x, d1.y),
                   (int)lo_pack(d2.x, d2.y), (int)lo_pack(d3.x, d3.y) };
      i32x4 f1 = { (int)lo_pack(e0.x, e0.y), (int)lo_pack(e1.x, e1.y),
                   (int)lo_pack(e2.x, e2.y), (int)lo_pack(e3.x, e3.y) };
      i32x4 f2v = { (int)hi_pack(d0.x, d0.y), (int)hi_pack(d1.x, d1.y),
                    (int)hi_pack(d2.x, d2.y), (int)hi_pack(d3.x, d3.y) };
      i32x4 f3 = { (int)hi_pack(e0.x, e0.y), (int)hi_pack(e1.x, e1.y),
                   (int)hi_pack(e2.x, e2.y), (int)hi_pack(e3.x, e3.y) };
      A1[cg * 4 + 0] = __builtin_bit_cast(bf16x8, f0);
      A1[cg * 4 + 1] = __builtin_bit_cast(bf16x8, f1);
      A1[cg * 4 + 2] = __builtin_bit_cast(bf16x8, f2v);
      A1[cg * 4 + 3] = __builtin_bit_cast(bf16x8, f3);
    }
  }

  unsigned int* scr3_w = scr3 + w * 1088;
  float* poolw = (float*)scr3;   // layer-2 per-wave pool partials (transpose dead by then)
  gcn_layer<16, 1>(w, lane, q, c, sig, packW + 4096,  B1, A1, A2, bndu, scr3_w, poolw);
  gcn_layer<16, 2>(w, lane, q, c, sig, packW + 69632, B2, A2, A1, bndu, scr3_w, poolw);

  __syncthreads();
  if (tid < 256) {
    float s = 0.f;
#pragma unroll
    for (int ww = 0; ww < 8; ++ww) s += poolw[ww * 256 + tid];
    out[b * 256 + tid] = s * (1.f / 256.f);
  }
}

// ---------------- launch ----------------
extern "C" void kernel_launch(void* const* d_in, const int* in_sizes, int n_in,
                              void* d_out, int out_size, void* d_ws, size_t ws_size,
                              hipStream_t stream) {
  const float* x  = (const float*)d_in[0];
  const float* t  = (const float*)d_in[1];
  const float* tw = (const float*)d_in[2];
  const float* tb = (const float*)d_in[3];
  const float* W0 = (const float*)d_in[4];
  const float* b0 = (const float*)d_in[5];
  const float* W1 = (const float*)d_in[6];
  const float* b1 = (const float*)d_in[7];
  const float* W2 = (const float*)d_in[8];
  const float* b2 = (const float*)d_in[9];

  unsigned short* packW = (unsigned short*)d_ws;   // 167936 shorts (L0:4096, L1:65536, L2:65536, W0mid:32768)
  float* out = (float*)d_out;

  pack_kernel<<<33, 512, 0, stream>>>(W0, W1, W2, packW);
  poly_kernel<<<1024, 512, 0, stream>>>(x, t, tw, tb, packW, b0, b1, b2, out);
}